// Round 3
// baseline (443.693 us; speedup 1.0000x reference)
//
#include <hip/hip_runtime.h>

// CrossAttention (B=8, Sq=Skv=2048, D=1024), fp32 in/out, bf16 MFMA compute.
//
// Full-batch pipeline (ws usage 107 MB; Q AND K parked in d_out as bf16):
//   1) cvt fp32->bf16: {x,ctx} -> xbf,cbf ; {Wq*(1/32),Wk,Wv} -> Wqb,Wkb,Wvb
//   2) [Q|K] = [x|ctx] @ [Wq|Wk]^T  (one batched NT GEMM) -> d_out bf16
//      Vt[b,e,t] = Wv@ctx^T (V transposed so PV is NT)    -> ws
//   3) S[b,s,t] = Q@K^T (8 batches) -> bf16 S overlays dead xbf+cbf
//   4) softmax rows in place (16384 rows)
//   5) out = P@Vt^T (f32) -> d_out, overwriting dead Q/K (stream-ordered)
//
// GEMM: 256x256 tile, BK=64, 8 waves (2Mx4N, each 128x64 via 8x4 frags of
// mfma_f32_16x16x32_bf16), 128 KiB STATIC LDS double buffer.
// Deep-pipelined schedule, m201-faithful phase structure:
//   - 4 phases per K-tile, each: {ds_read frags; issue stage; s_barrier;
//     setprio(1); 16 MFMA; setprio(0); s_barrier}. MFMA writes only acc ->
//     waves cross the post-MFMA barrier while the matrix pipe drains, and
//     the next phase's ds_reads overlap the drain (the m196/m218 lever).
//   - counted s_waitcnt vmcnt(4) twice per K-tile (never 0 in steady
//     state), placed before the trailing barrier of P2 (retires k1(t),
//     issued 3-4 phases earlier) and P4 (retires k0(t+1), 2-3 phases);
//   - LDS XOR swizzle slot^((row>>1)&3) on BOTH the pre-swizzled global
//     source column and the ds_read_b128 address (linear gload_lds dest,
//     "both-sides-or-neither") -> measured 0 bank conflicts (round 2);
//   - sched_barrier(0) after every s_barrier pins cross-barrier motion.
// 1D grid + XCD-aware swizzle: HW assigns XCD = blockIdx % 8 (round-robin);
// remap gid=(p%8)*slab+(p/8) gives each XCD a contiguous x-innermost slab.
// NOTE: grid size MUST equal nx*ny*nz exactly and be divisible by 8.

typedef unsigned short u16;
typedef __bf16 bf16x8 __attribute__((ext_vector_type(8)));
typedef float f32x4 __attribute__((ext_vector_type(4)));
typedef u16 us8 __attribute__((ext_vector_type(8)));

__device__ __forceinline__ u16 f2bf(float f) {
  unsigned int u = __float_as_uint(f);
  u += 0x7fffu + ((u >> 16) & 1u);   // round-to-nearest-even
  return (u16)(u >> 16);
}
__device__ __forceinline__ float bf2f(u16 h) {
  return __uint_as_float((unsigned int)h << 16);
}

struct __attribute__((aligned(8))) us4 { u16 x, y, z, w; };

// x (4194304 float4) -> xbf ; ctx -> cbf. One dispatch.
__global__ __launch_bounds__(256) void cvt_xc(const float4* __restrict__ x,
                                              const float4* __restrict__ c,
                                              us4* __restrict__ dx,
                                              us4* __restrict__ dc) {
  int i = blockIdx.x * 256 + threadIdx.x;
  const float4* s = (i < 4194304) ? x : (c - 4194304);
  us4* d = (i < 4194304) ? dx : (dc - 4194304);
  float4 v = s[i];
  us4 o{f2bf(v.x), f2bf(v.y), f2bf(v.z), f2bf(v.w)};
  d[i] = o;
}

// Wq*(1/32), Wk, Wv -> bf16 (each 262144 float4). One dispatch, 3072 blocks.
__global__ __launch_bounds__(256) void cvt_w(const float4* __restrict__ wq,
                                             const float4* __restrict__ wk,
                                             const float4* __restrict__ wv,
                                             us4* __restrict__ d) {
  int i = blockIdx.x * 256 + threadIdx.x;
  const float4* s; float sc;
  if (i < 262144)      { s = wq;           sc = 0.03125f; }
  else if (i < 524288) { s = wk - 262144;  sc = 1.0f; }
  else                 { s = wv - 524288;  sc = 1.0f; }
  float4 v = s[i];
  us4 o{f2bf(v.x * sc), f2bf(v.y * sc), f2bf(v.z * sc), f2bf(v.w * sc)};
  d[i] = o;
}

// C-style casts: static_cast cannot both drop const and change address space.
__device__ __forceinline__ void gload16(const u16* g, u16* l) {
  __builtin_amdgcn_global_load_lds(
      (const __attribute__((address_space(1))) unsigned int*)g,
      (__attribute__((address_space(3))) unsigned int*)l,
      16, 0, 0);
}

// NT GEMM: C[m,n] = sum_k A[m,k]*B[n,k].  A:[M][lda] B:[N][ldb] bf16
// row-major. 1D grid of EXACTLY nx*ny*nz blocks (divisible by 8), 512 thr.
template <bool BF16OUT>
__global__ __launch_bounds__(512, 2) void gemm_nt(
    const u16* __restrict__ A, const u16* __restrict__ B, void* __restrict__ Cout,
    int lda, int ldb, int ldc, int K,
    long batchA, long batchB, long batchC, int nx, int ny) {
  __shared__ u16 lds[65536];   // 128 KiB static
  // layout (u16 offs): buf b at b*32768; A k-half h at +h*8192 (256x32),
  // B at +16384 (+h*8192). Within a k-half: row r at r*32, 4 slots of 8.

  const int p    = blockIdx.x;
  const int slab = gridDim.x >> 3;
  const int gid  = (p & 7) * slab + (p >> 3);
  const int bx   = gid % nx;
  const int t2   = gid / nx;
  const int by   = t2 % ny;
  const int z    = t2 / ny;

  const int tid  = threadIdx.x;          // 0..511
  const int lane = tid & 63;
  const int wv   = tid >> 6;             // wave 0..7

  const u16* Ab = A + (size_t)z * batchA + (size_t)by * 256 * lda;
  const u16* Bb = B + (size_t)z * batchB + (size_t)bx * 256 * ldb;

  // staging: 512 threads, 4/row (64-B runs), 2 instrs cover 256 rows.
  // global col-group pre-swizzled: c = (tid&3) ^ ((row>>1)&3), row=tid>>2.
  const int srow = tid >> 2;                              // 0..127
  const int scol = ((tid & 3) ^ ((tid >> 3) & 3)) * 8;    // swizzled source

  const u16* gA = Ab + (size_t)srow * lda + scol;
  const u16* gB = Bb + (size_t)srow * ldb + scol;
  const size_t a128 = (size_t)128 * lda, b128 = (size_t)128 * ldb;

  u16* dA = &lds[tid * 8];           // + buf*32768 + h*8192 (+4096 instr 1)
  u16* dB = &lds[16384 + tid * 8];

  // fragment addressing (per wave: 128x64 tile, 8x4 frags of 16x16x32)
  const int fr = lane & 15;              // m (A) / n (B) within 16
  // phys slot = k-slot(lane>>4) ^ ((row>>1)&3); row>>1&3 == (fr>>1)&3 for
  // all mi/ni/wm/wn (all multiples of 8 rows) -> lane-constant xor.
  const int xw = (((lane >> 4) ^ ((lane >> 1) & 3)) * 8);
  const int wm = (wv >> 2) * 128;        // wave m-offset (0 or 128)
  const int wn = (wv & 3) * 64;          // wave n-offset (0..192)
  const int rA = (wm + fr) * 32 + xw;    // u16 offset within A k-half
  const int rB = (wn + fr) * 32 + xw;

  f32x4 acc[8][4];
#pragma unroll
  for (int i = 0; i < 8; i++)
#pragma unroll
    for (int j = 0; j < 4; j++) acc[i][j] = (f32x4)0.f;

  const int NTt = K >> 6;                // BK=64 tiles

#define STAGE_A(BUF, KT, H) do {                                  \
    const u16* g_ = gA + (size_t)(KT) * 64 + (H) * 32;            \
    u16* d_ = dA + ((BUF) << 15) + (H) * 8192;                    \
    gload16(g_, d_); gload16(g_ + a128, d_ + 4096); } while (0)
#define STAGE_B(BUF, KT, H) do {                                  \
    const u16* g_ = gB + (size_t)(KT) * 64 + (H) * 32;            \
    u16* d_ = dB + ((BUF) << 15) + (H) * 8192;                    \
    gload16(g_, d_); gload16(g_ + b128, d_ + 4096); } while (0)
#define LOAD_AV(H, ROFF) _Pragma("unroll")                        \
    for (int i_ = 0; i_ < 4; i_++)                                \
      av[i_] = *(const bf16x8*)&lds[cb + (H) * 8192 + rA + (ROFF) + i_ * 512];
#define LOAD_BV(H) _Pragma("unroll")                              \
    for (int i_ = 0; i_ < 4; i_++)                                \
      bv[i_] = *(const bf16x8*)&lds[cb + 16384 + (H) * 8192 + rB + i_ * 512];
#define MFMA16(AR)                                                \
    __builtin_amdgcn_s_setprio(1);                                \
    _Pragma("unroll")                                             \
    for (int mi_ = 0; mi_ < 4; mi_++)                             \
      _Pragma("unroll")                                           \
      for (int ni_ = 0; ni_ < 4; ni_++)                           \
        acc[(AR) + mi_][ni_] = __builtin_amdgcn_mfma_f32_16x16x32_bf16( \
            av[mi_], bv[ni_], acc[(AR) + mi_][ni_], 0, 0, 0);     \
    __builtin_amdgcn_s_setprio(0);
#define BARSB do { __builtin_amdgcn_s_barrier();                  \
    __builtin_amdgcn_sched_barrier(0); } while (0)

  // prologue: tile 0, issue order Ak0,Bk0,Ak1,Bk1 (8 loads); retire k0.
  STAGE_A(0, 0, 0); STAGE_B(0, 0, 0); STAGE_A(0, 0, 1); STAGE_B(0, 0, 1);
  asm volatile("s_waitcnt vmcnt(4)" ::: "memory");
  BARSB;

  for (int kt = 0; kt < NTt; ++kt) {
    const int cb = (kt & 1) << 15;       // current buffer (u16 offset)
    const int nb = (kt & 1) ^ 1;         // staging buffer index
    const bool pf = (kt + 1 < NTt);
    bf16x8 av[4], bv[4];

    // ---- P1: k0, acc[0-3] -------------------------------------------
    LOAD_AV(0, 0)
    LOAD_BV(0)
    if (pf) STAGE_A(nb, kt + 1, 0);
    BARSB;
    MFMA16(0)
    BARSB;

    // ---- P2: k0, acc[4-7] (bv reused); retire k1(t) -----------------
    LOAD_AV(0, 2048)
    if (pf) STAGE_B(nb, kt + 1, 0);
    BARSB;
    MFMA16(4)
    // k1(t) was issued at P3/P4 of tile t-1 (3-4 phases ago): counted.
    if (pf) { asm volatile("s_waitcnt vmcnt(4)" ::: "memory"); }
    else    { asm volatile("s_waitcnt vmcnt(0)" ::: "memory"); }
    BARSB;

    // ---- P3: k1, acc[0-3] -------------------------------------------
    LOAD_AV(1, 0)
    LOAD_BV(1)
    if (pf) STAGE_A(nb, kt + 1, 1);
    BARSB;
    MFMA16(0)
    BARSB;

    // ---- P4: k1, acc[4-7]; boundary retire k0(t+1) ------------------
    LOAD_AV(1, 2048)
    if (pf) STAGE_B(nb, kt + 1, 1);
    BARSB;
    MFMA16(4)
    // k0(t+1) was issued at P1/P2 of this tile (2-3 phases ago): counted.
    if (pf) {
      asm volatile("s_waitcnt vmcnt(4)" ::: "memory");
      BARSB;
    }
  }

  // epilogue: C/D layout col=lane&15, row=(lane>>4)*4+reg  [m89/m91 verified]
  const size_t cbase = (size_t)z * batchC;
  const int row0 = by * 256 + wm + (lane >> 4) * 4;
  const int col0 = bx * 256 + wn + fr;
#pragma unroll
  for (int mi = 0; mi < 8; mi++) {
#pragma unroll
    for (int i = 0; i < 4; i++) {
      const size_t roff = cbase + (size_t)(row0 + mi * 16 + i) * ldc + col0;
#pragma unroll
      for (int ni = 0; ni < 4; ni++) {
        float v = acc[mi][ni][i];
        if constexpr (BF16OUT)
          ((u16*)Cout)[roff + ni * 16] = f2bf(v);
        else
          ((float*)Cout)[roff + ni * 16] = v;
      }
    }
  }
#undef STAGE_A
#undef STAGE_B
#undef LOAD_AV
#undef LOAD_BV
#undef MFMA16
#undef BARSB
}

// One block per row of 2048 bf16 logits -> bf16 probabilities, IN PLACE.
__global__ __launch_bounds__(256) void softmax_rows_bf16(u16* __restrict__ SP) {
  const size_t row = blockIdx.x;
  us8* p = (us8*)(SP + row * 2048);
  const int t = threadIdx.x;
  us8 raw = p[t];
  float v[8];
#pragma unroll
  for (int i = 0; i < 8; i++) v[i] = bf2f(raw[i]);

  float m = v[0];
#pragma unroll
  for (int i = 1; i < 8; i++) m = fmaxf(m, v[i]);
#pragma unroll
  for (int o = 32; o; o >>= 1) m = fmaxf(m, __shfl_xor(m, o, 64));
  __shared__ float redm[4];
  if ((t & 63) == 0) redm[t >> 6] = m;
  __syncthreads();
  m = fmaxf(fmaxf(redm[0], redm[1]), fmaxf(redm[2], redm[3]));

  float sum = 0.f;
#pragma unroll
  for (int i = 0; i < 8; i++) { v[i] = __expf(v[i] - m); sum += v[i]; }
#pragma unroll
  for (int o = 32; o; o >>= 1) sum += __shfl_xor(sum, o, 64);
  __shared__ float reds[4];
  if ((t & 63) == 0) reds[t >> 6] = sum;
  __syncthreads();
  sum = reds[0] + reds[1] + reds[2] + reds[3];
  const float r = 1.0f / sum;

  us8 o;
#pragma unroll
  for (int i = 0; i < 8; i++) o[i] = f2bf(v[i] * r);
  p[t] = o;
}

extern "C" void kernel_launch(void* const* d_in, const int* in_sizes, int n_in,
                              void* d_out, int out_size, void* d_ws, size_t ws_size,
                              hipStream_t stream) {
  const float* x   = (const float*)d_in[0];  // [8,2048,1024]
  const float* ctx = (const float*)d_in[1];  // [8,2048,1024]
  const float* Wq  = (const float*)d_in[2];  // [1024,1024]
  const float* Wk  = (const float*)d_in[3];
  const float* Wv  = (const float*)d_in[4];
  float* out = (float*)d_out;                // [8,2048,1024] f32

  const size_t NT = 8ull * 2048 * 1024;      // 16,777,216 elements

  // d_ws layout (u16 elements; total 107 MB):
  //   xbf [0,NT)  cbf [NT,2NT)  -> both dead after projections -> S overlays
  //   Vt  [2NT,3NT)   Wqb/Wkb/Wvb [3NT, 3NT+3M)
  u16* wsu  = (u16*)d_ws;
  u16* xbf  = wsu;
  u16* cbf  = wsu + NT;
  u16* Sbuf = wsu;                 // overlays xbf+cbf (67 MB, 8 batches)
  u16* Vt   = wsu + 2 * NT;
  u16* Wqb  = wsu + 3 * NT;        // Wqb,Wkb,Wvb contiguous (1M elems each)
  // d_out doubles as bf16 Q [0,NT) and K [NT,2NT) until PV overwrites it.
  u16* Qbf = (u16*)d_out;

  dim3 blk(256), gblk(512);

  // 1) converts (2 dispatches)
  cvt_xc<<<dim3(32768), blk, 0, stream>>>((const float4*)x, (const float4*)ctx,
                                          (us4*)xbf, (us4*)cbf);
  cvt_w<<<dim3(3072), blk, 0, stream>>>((const float4*)Wq, (const float4*)Wk,
                                        (const float4*)Wv, (us4*)Wqb);

  // 2) [Q|K] projection: M=16384 N=1024 K=1024, z=0/1. nx*ny*nz=4*64*2=512.
  gemm_nt<true><<<dim3(512), gblk, 0, stream>>>(
      xbf, Wqb, Qbf, 1024, 1024, 1024, 1024,
      (long)NT, 1024L * 1024, (long)NT, 4, 64);
  // Vt[b,e,t] = Wv @ ctx_b^T : M=1024 N=2048 K=1024. nx*ny*nz=8*4*8=256.
  gemm_nt<true><<<dim3(256), gblk, 0, stream>>>(
      Wqb + 2 * 1024 * 1024, cbf, Vt, 1024, 1024, 2048, 1024,
      0L, 2048L * 1024, 1024L * 2048, 8, 4);

  // 3) S = Q@K^T : 8 batches, M=2048 N=2048 K=1024, bf16 out.
  //    nx*ny*nz = 8*8*8 = 512 blocks; slab=64 = one batch per XCD.
  gemm_nt<true><<<dim3(512), gblk, 0, stream>>>(
      Qbf, Qbf + NT, Sbuf, 1024, 1024, 2048, 1024,
      2048L * 1024, 2048L * 1024, 2048L * 2048, 8, 8);

  // 4) softmax in place: 16384 rows of 2048
  softmax_rows_bf16<<<dim3(16384), blk, 0, stream>>>(Sbuf);

  // 5) out = P@Vt^T : M=2048 N=1024 K=2048, f32 out. nx*ny*nz=4*8*8=256 ->
  //    one batch per XCD. Overwrites dead Q/K in d_out (stream-ordered).
  gemm_nt<false><<<dim3(256), gblk, 0, stream>>>(
      Sbuf, Vt, out, 2048, 2048, 1024, 2048,
      2048L * 2048, 1024L * 2048, 2048L * 1024, 4, 8);
}

// Round 4
// 438.745 us; speedup vs baseline: 1.0113x; 1.0113x over previous
//
#include <hip/hip_runtime.h>

// CrossAttention (B=8, Sq=Skv=2048, D=1024), fp32 in/out, bf16 MFMA compute.
//
// Full-batch pipeline (ws usage 107 MB; Q AND K parked in d_out as bf16):
//   1) cvt fp32->bf16: {x,ctx} -> xbf,cbf ; {Wq*(1/32),Wk,Wv} -> Wqb,Wkb,Wvb
//   2) [Q|K] = [x|ctx] @ [Wq|Wk]^T  (one batched NT GEMM) -> d_out bf16
//      Vt[b,e,t] = Wv@ctx^T (V transposed so PV is NT)    -> ws
//   3) S[b,s,t] = Q@K^T (8 batches) -> bf16 S overlays dead xbf+cbf
//   4) softmax rows in place (16384 rows)
//   5) out = P@Vt^T (f32) -> d_out, overwriting dead Q/K (stream-ordered)
//
// GEMM: 256x256 tile, BK=64, 8 waves (2Mx4N, each 128x64 via 8x4 frags of
// mfma_f32_16x16x32_bf16), 128 KiB static LDS double buffer.
// ROUND-4 CHANGE: all LDS fragment reads are inline-asm ds_read_b128.
// Rounds 0/2/3 all measured the same 33.5-35.5% MfmaUtil across three
// different source schedules -> diagnosis: compiler orders the RAW between
// global_load_lds (unknown LDS write) and C++ ds_reads by inserting its own
// conservative vmcnt waits, collapsing the counted-vmcnt pipeline to the
// m97 drain-per-phase form. Volatile-asm reads are ordered only by my
// explicit asm waitcnts + side-effecting barrier intrinsics, so the
// hand-counted vmcnt(4) discipline actually reaches the hardware.
//   - 4 phases per K-tile: {asm ds_read frags; issue stage; s_barrier;
//     asm lgkmcnt(0); sched_barrier(0) [rule 18]; setprio(1); 16 MFMA;
//     setprio(0); s_barrier}.
//   - counted s_waitcnt vmcnt(4) twice per K-tile (never 0 until the last
//     tile): P2 retires k1(t) (issued 3-4 phases earlier), P4 retires
//     k0(t+1) (issued 2-3 phases earlier).
//   - LDS XOR swizzle slot^((row>>1)&3) on BOTH the pre-swizzled global
//     source column and the ds_read address (linear gload_lds dest,
//     "both-sides-or-neither") -> measured 0 bank conflicts (round 2).
// 1D grid + XCD-aware swizzle: HW assigns XCD = blockIdx % 8 (round-robin);
// remap gid=(p%8)*slab+(p/8) gives each XCD a contiguous x-innermost slab.
// NOTE: grid size MUST equal nx*ny*nz exactly and be divisible by 8.

typedef unsigned short u16;
typedef __bf16 bf16x8 __attribute__((ext_vector_type(8)));
typedef float f32x4 __attribute__((ext_vector_type(4)));
typedef u16 us8 __attribute__((ext_vector_type(8)));

__device__ __forceinline__ u16 f2bf(float f) {
  unsigned int u = __float_as_uint(f);
  u += 0x7fffu + ((u >> 16) & 1u);   // round-to-nearest-even
  return (u16)(u >> 16);
}
__device__ __forceinline__ float bf2f(u16 h) {
  return __uint_as_float((unsigned int)h << 16);
}

struct __attribute__((aligned(8))) us4 { u16 x, y, z, w; };

// x (4194304 float4) -> xbf ; ctx -> cbf. One dispatch.
__global__ __launch_bounds__(256) void cvt_xc(const float4* __restrict__ x,
                                              const float4* __restrict__ c,
                                              us4* __restrict__ dx,
                                              us4* __restrict__ dc) {
  int i = blockIdx.x * 256 + threadIdx.x;
  const float4* s = (i < 4194304) ? x : (c - 4194304);
  us4* d = (i < 4194304) ? dx : (dc - 4194304);
  float4 v = s[i];
  us4 o{f2bf(v.x), f2bf(v.y), f2bf(v.z), f2bf(v.w)};
  d[i] = o;
}

// Wq*(1/32), Wk, Wv -> bf16 (each 262144 float4). One dispatch, 3072 blocks.
__global__ __launch_bounds__(256) void cvt_w(const float4* __restrict__ wq,
                                             const float4* __restrict__ wk,
                                             const float4* __restrict__ wv,
                                             us4* __restrict__ d) {
  int i = blockIdx.x * 256 + threadIdx.x;
  const float4* s; float sc;
  if (i < 262144)      { s = wq;           sc = 0.03125f; }
  else if (i < 524288) { s = wk - 262144;  sc = 1.0f; }
  else                 { s = wv - 524288;  sc = 1.0f; }
  float4 v = s[i];
  us4 o{f2bf(v.x * sc), f2bf(v.y * sc), f2bf(v.z * sc), f2bf(v.w * sc)};
  d[i] = o;
}

// C-style casts: static_cast cannot both drop const and change address space.
__device__ __forceinline__ void gload16(const u16* g, u16* l) {
  __builtin_amdgcn_global_load_lds(
      (const __attribute__((address_space(1))) unsigned int*)g,
      (__attribute__((address_space(3))) unsigned int*)l,
      16, 0, 0);
}

// NT GEMM: C[m,n] = sum_k A[m,k]*B[n,k].  A:[M][lda] B:[N][ldb] bf16
// row-major. 1D grid of EXACTLY nx*ny*nz blocks (divisible by 8), 512 thr.
template <bool BF16OUT>
__global__ __launch_bounds__(512, 2) void gemm_nt(
    const u16* __restrict__ A, const u16* __restrict__ B, void* __restrict__ Cout,
    int lda, int ldb, int ldc, int K,
    long batchA, long batchB, long batchC, int nx, int ny) {
  __shared__ u16 lds[65536];   // 128 KiB static
  // layout (u16 offs): buf b at b*32768; A k-half h at +h*8192 (256x32),
  // B at +16384 (+h*8192). Within a k-half: row r at r*32, 4 slots of 8.

  const int p    = blockIdx.x;
  const int slab = gridDim.x >> 3;
  const int gid  = (p & 7) * slab + (p >> 3);
  const int bx   = gid % nx;
  const int t2   = gid / nx;
  const int by   = t2 % ny;
  const int z    = t2 / ny;

  const int tid  = threadIdx.x;          // 0..511
  const int lane = tid & 63;
  const int wv   = tid >> 6;             // wave 0..7

  const u16* Ab = A + (size_t)z * batchA + (size_t)by * 256 * lda;
  const u16* Bb = B + (size_t)z * batchB + (size_t)bx * 256 * ldb;

  // staging: 512 threads, 4/row (64-B runs), 2 instrs cover 256 rows.
  // global col-group pre-swizzled: c = (tid&3) ^ ((row>>1)&3), row=tid>>2.
  const int srow = tid >> 2;                              // 0..127
  const int scol = ((tid & 3) ^ ((tid >> 3) & 3)) * 8;    // swizzled source

  const u16* gA = Ab + (size_t)srow * lda + scol;
  const u16* gB = Bb + (size_t)srow * ldb + scol;
  const size_t a128 = (size_t)128 * lda, b128 = (size_t)128 * ldb;

  u16* dA = &lds[tid * 8];           // + buf*32768 + h*8192 (+4096 instr 1)
  u16* dB = &lds[16384 + tid * 8];

  // fragment addressing (per wave: 128x64 tile, 8x4 frags of 16x16x32)
  const int fr = lane & 15;              // m (A) / n (B) within 16
  // phys slot = k-slot(lane>>4) ^ ((row>>1)&3); row>>1&3 == (fr>>1)&3 for
  // all mi/ni/wm/wn (all multiples of 8 rows) -> lane-constant xor.
  const int xw = (((lane >> 4) ^ ((lane >> 1) & 3)) * 8);
  const int wm = (wv >> 2) * 128;        // wave m-offset (0 or 128)
  const int wn = (wv & 3) * 64;          // wave n-offset (0..192)
  const int rA = (wm + fr) * 32 + xw;    // u16 offset within A k-half
  const int rB = (wn + fr) * 32 + xw;

  // byte addresses for inline-asm ds_read (buffer 0; buffer 1 = +65536 B)
  const unsigned ldsb = (unsigned)(size_t)&lds[0];
  const unsigned bA0 = ldsb + (unsigned)(rA * 2);
  const unsigned bB0 = ldsb + 32768u + (unsigned)(rB * 2);

  f32x4 acc[8][4];
#pragma unroll
  for (int i = 0; i < 8; i++)
#pragma unroll
    for (int j = 0; j < 4; j++) acc[i][j] = (f32x4)0.f;

  const int NTt = K >> 6;                // BK=64 tiles

#define STAGE_A(BUF, KT, H) do {                                  \
    const u16* g_ = gA + (size_t)(KT) * 64 + (H) * 32;            \
    u16* d_ = dA + ((BUF) << 15) + (H) * 8192;                    \
    gload16(g_, d_); gload16(g_ + a128, d_ + 4096); } while (0)
#define STAGE_B(BUF, KT, H) do {                                  \
    const u16* g_ = gB + (size_t)(KT) * 64 + (H) * 32;            \
    u16* d_ = dB + ((BUF) << 15) + (H) * 8192;                    \
    gload16(g_, d_); gload16(g_ + b128, d_ + 4096); } while (0)
// volatile asm ds_read: compiler cannot attach its own waitcnt to it, and
// program order vs the barrier/gload intrinsics + asm waitcnts is kept.
#define DSR(D, BASE, IMM)                                         \
    asm volatile("ds_read_b128 %0, %1 offset:" #IMM               \
                 : "=v"(D) : "v"(BASE))
// rule #18: lgkmcnt(0) via asm REQUIRES a following sched_barrier(0) or
// hipcc hoists register-only MFMAs above the wait.
#define LGKM0 do { asm volatile("s_waitcnt lgkmcnt(0)" ::: "memory"); \
    __builtin_amdgcn_sched_barrier(0); } while (0)
#define MFMA16(AR)                                                \
    __builtin_amdgcn_s_setprio(1);                                \
    _Pragma("unroll")                                             \
    for (int mi_ = 0; mi_ < 4; mi_++)                             \
      _Pragma("unroll")                                           \
      for (int ni_ = 0; ni_ < 4; ni_++)                           \
        acc[(AR) + mi_][ni_] = __builtin_amdgcn_mfma_f32_16x16x32_bf16( \
            __builtin_bit_cast(bf16x8, av[mi_]),                  \
            __builtin_bit_cast(bf16x8, bv[ni_]),                  \
            acc[(AR) + mi_][ni_], 0, 0, 0);                       \
    __builtin_amdgcn_s_setprio(0);

  // prologue: tile 0, issue order Ak0,Bk0,Ak1,Bk1 (8 loads); retire k0.
  STAGE_A(0, 0, 0); STAGE_B(0, 0, 0); STAGE_A(0, 0, 1); STAGE_B(0, 0, 1);
  asm volatile("s_waitcnt vmcnt(4)" ::: "memory");
  __builtin_amdgcn_s_barrier();

  for (int kt = 0; kt < NTt; ++kt) {
    const unsigned bufo = (kt & 1) ? 65536u : 0u;   // current buffer (bytes)
    const unsigned bA = bA0 + bufo;
    const unsigned bB = bB0 + bufo;
    const int nb = (kt & 1) ^ 1;         // staging buffer index
    const bool pf = (kt + 1 < NTt);
    f32x4 av[4], bv[4];

    // ---- P1: k0, acc[0-3] -------------------------------------------
    DSR(av[0], bA, 0);     DSR(av[1], bA, 1024);
    DSR(av[2], bA, 2048);  DSR(av[3], bA, 3072);
    DSR(bv[0], bB, 0);     DSR(bv[1], bB, 1024);
    DSR(bv[2], bB, 2048);  DSR(bv[3], bB, 3072);
    if (pf) STAGE_A(nb, kt + 1, 0);
    __builtin_amdgcn_s_barrier();
    LGKM0;
    MFMA16(0)
    __builtin_amdgcn_s_barrier();

    // ---- P2: k0, acc[4-7] (bv reused); retire k1(t) -----------------
    DSR(av[0], bA, 4096);  DSR(av[1], bA, 5120);
    DSR(av[2], bA, 6144);  DSR(av[3], bA, 7168);
    if (pf) STAGE_B(nb, kt + 1, 0);
    __builtin_amdgcn_s_barrier();
    LGKM0;
    MFMA16(4)
    // k1(t) was issued at P3/P4 of tile t-1 (3-4 phases ago): counted.
    if (pf) { asm volatile("s_waitcnt vmcnt(4)" ::: "memory"); }
    else    { asm volatile("s_waitcnt vmcnt(0)" ::: "memory"); }
    __builtin_amdgcn_s_barrier();

    // ---- P3: k1, acc[0-3] -------------------------------------------
    DSR(av[0], bA, 16384); DSR(av[1], bA, 17408);
    DSR(av[2], bA, 18432); DSR(av[3], bA, 19456);
    DSR(bv[0], bB, 16384); DSR(bv[1], bB, 17408);
    DSR(bv[2], bB, 18432); DSR(bv[3], bB, 19456);
    if (pf) STAGE_A(nb, kt + 1, 1);
    __builtin_amdgcn_s_barrier();
    LGKM0;
    MFMA16(0)
    __builtin_amdgcn_s_barrier();

    // ---- P4: k1, acc[4-7]; boundary retire k0(t+1) ------------------
    DSR(av[0], bA, 20480); DSR(av[1], bA, 21504);
    DSR(av[2], bA, 22528); DSR(av[3], bA, 23552);
    if (pf) STAGE_B(nb, kt + 1, 1);
    __builtin_amdgcn_s_barrier();
    LGKM0;
    MFMA16(4)
    // k0(t+1) was issued at P1/P2 of this tile (2-3 phases ago): counted.
    if (pf) {
      asm volatile("s_waitcnt vmcnt(4)" ::: "memory");
      __builtin_amdgcn_s_barrier();
    }
  }

  // epilogue: C/D layout col=lane&15, row=(lane>>4)*4+reg  [m89/m91 verified]
  const size_t cbase = (size_t)z * batchC;
  const int row0 = by * 256 + wm + (lane >> 4) * 4;
  const int col0 = bx * 256 + wn + fr;
#pragma unroll
  for (int mi = 0; mi < 8; mi++) {
#pragma unroll
    for (int i = 0; i < 4; i++) {
      const size_t roff = cbase + (size_t)(row0 + mi * 16 + i) * ldc + col0;
#pragma unroll
      for (int ni = 0; ni < 4; ni++) {
        float v = acc[mi][ni][i];
        if constexpr (BF16OUT)
          ((u16*)Cout)[roff + ni * 16] = f2bf(v);
        else
          ((float*)Cout)[roff + ni * 16] = v;
      }
    }
  }
#undef STAGE_A
#undef STAGE_B
#undef DSR
#undef LGKM0
#undef MFMA16
}

// One block per row of 2048 bf16 logits -> bf16 probabilities, IN PLACE.
__global__ __launch_bounds__(256) void softmax_rows_bf16(u16* __restrict__ SP) {
  const size_t row = blockIdx.x;
  us8* p = (us8*)(SP + row * 2048);
  const int t = threadIdx.x;
  us8 raw = p[t];
  float v[8];
#pragma unroll
  for (int i = 0; i < 8; i++) v[i] = bf2f(raw[i]);

  float m = v[0];
#pragma unroll
  for (int i = 1; i < 8; i++) m = fmaxf(m, v[i]);
#pragma unroll
  for (int o = 32; o; o >>= 1) m = fmaxf(m, __shfl_xor(m, o, 64));
  __shared__ float redm[4];
  if ((t & 63) == 0) redm[t >> 6] = m;
  __syncthreads();
  m = fmaxf(fmaxf(redm[0], redm[1]), fmaxf(redm[2], redm[3]));

  float sum = 0.f;
#pragma unroll
  for (int i = 0; i < 8; i++) { v[i] = __expf(v[i] - m); sum += v[i]; }
#pragma unroll
  for (int o = 32; o; o >>= 1) sum += __shfl_xor(sum, o, 64);
  __shared__ float reds[4];
  if ((t & 63) == 0) reds[t >> 6] = sum;
  __syncthreads();
  sum = reds[0] + reds[1] + reds[2] + reds[3];
  const float r = 1.0f / sum;

  us8 o;
#pragma unroll
  for (int i = 0; i < 8; i++) o[i] = f2bf(v[i] * r);
  p[t] = o;
}

extern "C" void kernel_launch(void* const* d_in, const int* in_sizes, int n_in,
                              void* d_out, int out_size, void* d_ws, size_t ws_size,
                              hipStream_t stream) {
  const float* x   = (const float*)d_in[0];  // [8,2048,1024]
  const float* ctx = (const float*)d_in[1];  // [8,2048,1024]
  const float* Wq  = (const float*)d_in[2];  // [1024,1024]
  const float* Wk  = (const float*)d_in[3];
  const float* Wv  = (const float*)d_in[4];
  float* out = (float*)d_out;                // [8,2048,1024] f32

  const size_t NT = 8ull * 2048 * 1024;      // 16,777,216 elements

  // d_ws layout (u16 elements; total 107 MB):
  //   xbf [0,NT)  cbf [NT,2NT)  -> both dead after projections -> S overlays
  //   Vt  [2NT,3NT)   Wqb/Wkb/Wvb [3NT, 3NT+3M)
  u16* wsu  = (u16*)d_ws;
  u16* xbf  = wsu;
  u16* cbf  = wsu + NT;
  u16* Sbuf = wsu;                 // overlays xbf+cbf (67 MB, 8 batches)
  u16* Vt   = wsu + 2 * NT;
  u16* Wqb  = wsu + 3 * NT;        // Wqb,Wkb,Wvb contiguous (1M elems each)
  // d_out doubles as bf16 Q [0,NT) and K [NT,2NT) until PV overwrites it.
  u16* Qbf = (u16*)d_out;

  dim3 blk(256), gblk(512);

  // 1) converts (2 dispatches)
  cvt_xc<<<dim3(32768), blk, 0, stream>>>((const float4*)x, (const float4*)ctx,
                                          (us4*)xbf, (us4*)cbf);
  cvt_w<<<dim3(3072), blk, 0, stream>>>((const float4*)Wq, (const float4*)Wk,
                                        (const float4*)Wv, (us4*)Wqb);

  // 2) [Q|K] projection: M=16384 N=1024 K=1024, z=0/1. nx*ny*nz=4*64*2=512.
  gemm_nt<true><<<dim3(512), gblk, 0, stream>>>(
      xbf, Wqb, Qbf, 1024, 1024, 1024, 1024,
      (long)NT, 1024L * 1024, (long)NT, 4, 64);
  // Vt[b,e,t] = Wv @ ctx_b^T : M=1024 N=2048 K=1024. nx*ny*nz=8*4*8=256.
  gemm_nt<true><<<dim3(256), gblk, 0, stream>>>(
      Wqb + 2 * 1024 * 1024, cbf, Vt, 1024, 1024, 2048, 1024,
      0L, 2048L * 1024, 1024L * 2048, 8, 4);

  // 3) S = Q@K^T : 8 batches, M=2048 N=2048 K=1024, bf16 out.
  //    nx*ny*nz = 8*8*8 = 512 blocks; slab=64 = one batch per XCD.
  gemm_nt<true><<<dim3(512), gblk, 0, stream>>>(
      Qbf, Qbf + NT, Sbuf, 1024, 1024, 2048, 1024,
      2048L * 1024, 2048L * 1024, 2048L * 2048, 8, 8);

  // 4) softmax in place: 16384 rows of 2048
  softmax_rows_bf16<<<dim3(16384), blk, 0, stream>>>(Sbuf);

  // 5) out = P@Vt^T : M=2048 N=1024 K=2048, f32 out. nx*ny*nz=4*8*8=256 ->
  //    one batch per XCD. Overwrites dead Q/K in d_out (stream-ordered).
  gemm_nt<false><<<dim3(256), gblk, 0, stream>>>(
      Sbuf, Vt, out, 2048, 2048, 1024, 2048,
      2048L * 2048, 1024L * 2048, 2048L * 1024, 4, 8);
}

// Round 5
// 429.065 us; speedup vs baseline: 1.0341x; 1.0226x over previous
//
#include <hip/hip_runtime.h>

// CrossAttention (B=8, Sq=Skv=2048, D=1024), fp32 in/out, bf16 MFMA compute.
//
// Full-batch pipeline (ws usage 107 MB; Q AND K parked in d_out as bf16):
//   1) cvt fp32->bf16: {x,ctx} -> xbf,cbf ; {Wq*(1/32),Wk,Wv} -> Wqb,Wkb,Wvb
//   2) [Q|K] = [x|ctx] @ [Wq|Wk]^T  (one batched NT GEMM) -> d_out bf16
//      Vt[b,e,t] = Wv@ctx^T (V transposed so PV is NT)    -> ws
//   3) S[b,s,t] = Q@K^T (8 batches) -> bf16 S overlays dead xbf+cbf
//   4) softmax rows in place (16384 rows)
//   5) out = P@Vt^T (f32) -> d_out, overwriting dead Q/K (stream-ordered)
//
// GEMM: 256x256 tile, BK=64, 8 waves (2Mx4N, each 128x64 via 8x4 frags of
// mfma_f32_16x16x32_bf16), 128 KiB static LDS double buffer.
// ROUND-5 CHANGE: counted LGKMCNT + reads-ahead, ONE barrier per K-tile.
// Model fit (r4): per-tile = LDS-reads 2260cy + MFMA 2064cy SERIAL = 5790cy
// measured; MfmaUtil 2064/5790 = 35.6% = measured 36%. Cause: lgkmcnt(0)
// before every MFMA cluster + per-phase barriers serialize LDS pipe and
// matrix pipe. Fix: within a K-tile the read-buffer is stable (staging goes
// to the other buffer), so intra-tile barriers are unnecessary; issue reads
// for future clusters EARLY and wait with counted lgkmcnt for exactly the
// fragments the next cluster needs (DS ops retire in order):
//   R(a0,b0,a1)=12; stage all 4 half-tiles of t+1; lgkm(4); MFMA(a0xb0);
//   R(c0,d0)=8; lgkm(8); MFMA(a1xb0); R(c1)=4; lgkm(4); MFMA(c0xd0);
//   lgkm(0); MFMA(c1xd0); vmcnt(0); s_barrier.   [one barrier/tile]
// Boundary vmcnt(0) is cheap: newest gload was issued a full tile (~3000cy)
// earlier. sched_barrier(0) after each waitcnt (rule 18) and after the
// barrier pins motion. LDS XOR swizzle slot^((row>>1)&3) on both the
// pre-swizzled global source column and the ds_read address -> 0 conflicts
// (measured r2). s_setprio(1) around MFMA clusters.
// 1D grid + XCD-aware swizzle: HW assigns XCD = blockIdx % 8 (round-robin);
// remap gid=(p%8)*slab+(p/8) gives each XCD a contiguous x-innermost slab.
// NOTE: grid size MUST equal nx*ny*nz exactly and be divisible by 8.

typedef unsigned short u16;
typedef __bf16 bf16x8 __attribute__((ext_vector_type(8)));
typedef float f32x4 __attribute__((ext_vector_type(4)));
typedef u16 us8 __attribute__((ext_vector_type(8)));

__device__ __forceinline__ u16 f2bf(float f) {
  unsigned int u = __float_as_uint(f);
  u += 0x7fffu + ((u >> 16) & 1u);   // round-to-nearest-even
  return (u16)(u >> 16);
}
__device__ __forceinline__ float bf2f(u16 h) {
  return __uint_as_float((unsigned int)h << 16);
}

struct __attribute__((aligned(8))) us4 { u16 x, y, z, w; };

// x (4194304 float4) -> xbf ; ctx -> cbf. One dispatch.
__global__ __launch_bounds__(256) void cvt_xc(const float4* __restrict__ x,
                                              const float4* __restrict__ c,
                                              us4* __restrict__ dx,
                                              us4* __restrict__ dc) {
  int i = blockIdx.x * 256 + threadIdx.x;
  const float4* s = (i < 4194304) ? x : (c - 4194304);
  us4* d = (i < 4194304) ? dx : (dc - 4194304);
  float4 v = s[i];
  us4 o{f2bf(v.x), f2bf(v.y), f2bf(v.z), f2bf(v.w)};
  d[i] = o;
}

// Wq*(1/32), Wk, Wv -> bf16 (each 262144 float4). One dispatch, 3072 blocks.
__global__ __launch_bounds__(256) void cvt_w(const float4* __restrict__ wq,
                                             const float4* __restrict__ wk,
                                             const float4* __restrict__ wv,
                                             us4* __restrict__ d) {
  int i = blockIdx.x * 256 + threadIdx.x;
  const float4* s; float sc;
  if (i < 262144)      { s = wq;           sc = 0.03125f; }
  else if (i < 524288) { s = wk - 262144;  sc = 1.0f; }
  else                 { s = wv - 524288;  sc = 1.0f; }
  float4 v = s[i];
  us4 o{f2bf(v.x * sc), f2bf(v.y * sc), f2bf(v.z * sc), f2bf(v.w * sc)};
  d[i] = o;
}

// C-style casts: static_cast cannot both drop const and change address space.
__device__ __forceinline__ void gload16(const u16* g, u16* l) {
  __builtin_amdgcn_global_load_lds(
      (const __attribute__((address_space(1))) unsigned int*)g,
      (__attribute__((address_space(3))) unsigned int*)l,
      16, 0, 0);
}

// NT GEMM: C[m,n] = sum_k A[m,k]*B[n,k].  A:[M][lda] B:[N][ldb] bf16
// row-major. 1D grid of EXACTLY nx*ny*nz blocks (divisible by 8), 512 thr.
template <bool BF16OUT>
__global__ __launch_bounds__(512, 2) void gemm_nt(
    const u16* __restrict__ A, const u16* __restrict__ B, void* __restrict__ Cout,
    int lda, int ldb, int ldc, int K,
    long batchA, long batchB, long batchC, int nx, int ny) {
  __shared__ u16 lds[65536];   // 128 KiB static
  // layout (u16 offs): buf b at b*32768; A k-half h at +h*8192 (256x32),
  // B at +16384 (+h*8192). Within a k-half: row r at r*32, 4 slots of 8.

  const int p    = blockIdx.x;
  const int slab = gridDim.x >> 3;
  const int gid  = (p & 7) * slab + (p >> 3);
  const int bx   = gid % nx;
  const int t2   = gid / nx;
  const int by   = t2 % ny;
  const int z    = t2 / ny;

  const int tid  = threadIdx.x;          // 0..511
  const int lane = tid & 63;
  const int wv   = tid >> 6;             // wave 0..7

  const u16* Ab = A + (size_t)z * batchA + (size_t)by * 256 * lda;
  const u16* Bb = B + (size_t)z * batchB + (size_t)bx * 256 * ldb;

  // staging: 512 threads, 4/row (64-B runs), 2 instrs cover 256 rows.
  // global col-group pre-swizzled: c = (tid&3) ^ ((row>>1)&3), row=tid>>2.
  const int srow = tid >> 2;                              // 0..127
  const int scol = ((tid & 3) ^ ((tid >> 3) & 3)) * 8;    // swizzled source

  const u16* gA = Ab + (size_t)srow * lda + scol;
  const u16* gB = Bb + (size_t)srow * ldb + scol;
  const size_t a128 = (size_t)128 * lda, b128 = (size_t)128 * ldb;

  u16* dA = &lds[tid * 8];           // + buf*32768 + h*8192 (+4096 instr 1)
  u16* dB = &lds[16384 + tid * 8];

  // fragment addressing (per wave: 128x64 tile, 8x4 frags of 16x16x32)
  const int fr = lane & 15;              // m (A) / n (B) within 16
  // phys slot = k-slot(lane>>4) ^ ((row>>1)&3); row>>1&3 == (fr>>1)&3 for
  // all mi/ni/wm/wn (all multiples of 8 rows) -> lane-constant xor.
  const int xw = (((lane >> 4) ^ ((lane >> 1) & 3)) * 8);
  const int wm = (wv >> 2) * 128;        // wave m-offset (0 or 128)
  const int wn = (wv & 3) * 64;          // wave n-offset (0..192)
  const int rA = (wm + fr) * 32 + xw;    // u16 offset within A k-half
  const int rB = (wn + fr) * 32 + xw;

  // byte addresses for inline-asm ds_read (buffer 0; buffer 1 = +65536 B)
  const unsigned ldsb = (unsigned)(size_t)&lds[0];
  const unsigned bA0 = ldsb + (unsigned)(rA * 2);
  const unsigned bB0 = ldsb + 32768u + (unsigned)(rB * 2);

  f32x4 acc[8][4];
#pragma unroll
  for (int i = 0; i < 8; i++)
#pragma unroll
    for (int j = 0; j < 4; j++) acc[i][j] = (f32x4)0.f;

  const int NTt = K >> 6;                // BK=64 tiles

#define STAGE_A(BUF, KT, H) do {                                  \
    const u16* g_ = gA + (size_t)(KT) * 64 + (H) * 32;            \
    u16* d_ = dA + ((BUF) << 15) + (H) * 8192;                    \
    gload16(g_, d_); gload16(g_ + a128, d_ + 4096); } while (0)
#define STAGE_B(BUF, KT, H) do {                                  \
    const u16* g_ = gB + (size_t)(KT) * 64 + (H) * 32;            \
    u16* d_ = dB + ((BUF) << 15) + (H) * 8192;                    \
    gload16(g_, d_); gload16(g_ + b128, d_ + 4096); } while (0)
// volatile asm ds_read: compiler cannot attach its own waitcnt to it; all
// ordering vs waits/barriers is explicit.
#define DSR(D, BASE, IMM)                                         \
    asm volatile("ds_read_b128 %0, %1 offset:" #IMM               \
                 : "=v"(D) : "v"(BASE))
// rule #18: asm waitcnt REQUIRES a following sched_barrier(0) or hipcc
// hoists register-only MFMAs above the wait.
#define LGKM(N) do {                                              \
    asm volatile("s_waitcnt lgkmcnt(" #N ")" ::: "memory");       \
    __builtin_amdgcn_sched_barrier(0); } while (0)
#define MFMA16(AR, AV, BV)                                        \
    __builtin_amdgcn_s_setprio(1);                                \
    _Pragma("unroll")                                             \
    for (int mi_ = 0; mi_ < 4; mi_++)                             \
      _Pragma("unroll")                                           \
      for (int ni_ = 0; ni_ < 4; ni_++)                           \
        acc[(AR) + mi_][ni_] = __builtin_amdgcn_mfma_f32_16x16x32_bf16( \
            __builtin_bit_cast(bf16x8, AV[mi_]),                  \
            __builtin_bit_cast(bf16x8, BV[ni_]),                  \
            acc[(AR) + mi_][ni_], 0, 0, 0);                       \
    __builtin_amdgcn_s_setprio(0);

  // prologue: stage all of tile 0, drain, publish. (Loop reads BOTH k-halves
  // of the current buffer early, so the full tile must be resident.)
  STAGE_A(0, 0, 0); STAGE_B(0, 0, 0); STAGE_A(0, 0, 1); STAGE_B(0, 0, 1);
  asm volatile("s_waitcnt vmcnt(0)" ::: "memory");
  __builtin_amdgcn_s_barrier();
  __builtin_amdgcn_sched_barrier(0);

  for (int kt = 0; kt < NTt; ++kt) {
    const unsigned bufo = (kt & 1) ? 65536u : 0u;   // current buffer (bytes)
    const unsigned bA = bA0 + bufo;
    const unsigned bB = bB0 + bufo;
    const int nb = (kt & 1) ^ 1;         // staging buffer index
    const bool pf = (kt + 1 < NTt);
    f32x4 a0[4], a1[4], b0[4], c0[4], c1[4], d0[4];

    // ---- k-half 0: issue ALL 12 reads, then stage whole next tile ----
    DSR(a0[0], bA, 0);     DSR(a0[1], bA, 1024);
    DSR(a0[2], bA, 2048);  DSR(a0[3], bA, 3072);
    DSR(b0[0], bB, 0);     DSR(b0[1], bB, 1024);
    DSR(b0[2], bB, 2048);  DSR(b0[3], bB, 3072);
    DSR(a1[0], bA, 4096);  DSR(a1[1], bA, 5120);
    DSR(a1[2], bA, 6144);  DSR(a1[3], bA, 7168);
    if (pf) { STAGE_A(nb, kt + 1, 0); STAGE_B(nb, kt + 1, 0);
              STAGE_A(nb, kt + 1, 1); STAGE_B(nb, kt + 1, 1); }

    LGKM(4);              // a0,b0 ready; a1 (4) still in flight
    MFMA16(0, a0, b0)

    // ---- k-half 1 reads fly under the a1xb0 cluster ------------------
    DSR(c0[0], bA, 16384); DSR(c0[1], bA, 17408);
    DSR(c0[2], bA, 18432); DSR(c0[3], bA, 19456);
    DSR(d0[0], bB, 16384); DSR(d0[1], bB, 17408);
    DSR(d0[2], bB, 18432); DSR(d0[3], bB, 19456);
    LGKM(8);              // a1 ready; c0,d0 (8) in flight
    MFMA16(4, a1, b0)

    DSR(c1[0], bA, 20480); DSR(c1[1], bA, 21504);
    DSR(c1[2], bA, 22528); DSR(c1[3], bA, 23552);
    LGKM(4);              // c0,d0 ready; c1 (4) in flight
    MFMA16(0, c0, d0)
    LGKM(0);              // c1 ready
    MFMA16(4, c1, d0)

    // buffer handoff: the ONE barrier per tile. vmcnt(0) retires the 8
    // stages issued at the top of this tile (~3000 cy cover).
    if (pf) {
      asm volatile("s_waitcnt vmcnt(0)" ::: "memory");
      __builtin_amdgcn_s_barrier();
      __builtin_amdgcn_sched_barrier(0);
    }
  }

  // epilogue: C/D layout col=lane&15, row=(lane>>4)*4+reg  [m89/m91 verified]
  const size_t cbase = (size_t)z * batchC;
  const int row0 = by * 256 + wm + (lane >> 4) * 4;
  const int col0 = bx * 256 + wn + fr;
#pragma unroll
  for (int mi = 0; mi < 8; mi++) {
#pragma unroll
    for (int i = 0; i < 4; i++) {
      const size_t roff = cbase + (size_t)(row0 + mi * 16 + i) * ldc + col0;
#pragma unroll
      for (int ni = 0; ni < 4; ni++) {
        float v = acc[mi][ni][i];
        if constexpr (BF16OUT)
          ((u16*)Cout)[roff + ni * 16] = f2bf(v);
        else
          ((float*)Cout)[roff + ni * 16] = v;
      }
    }
  }
#undef STAGE_A
#undef STAGE_B
#undef DSR
#undef LGKM
#undef MFMA16
}

// One block per row of 2048 bf16 logits -> bf16 probabilities, IN PLACE.
__global__ __launch_bounds__(256) void softmax_rows_bf16(u16* __restrict__ SP) {
  const size_t row = blockIdx.x;
  us8* p = (us8*)(SP + row * 2048);
  const int t = threadIdx.x;
  us8 raw = p[t];
  float v[8];
#pragma unroll
  for (int i = 0; i < 8; i++) v[i] = bf2f(raw[i]);

  float m = v[0];
#pragma unroll
  for (int i = 1; i < 8; i++) m = fmaxf(m, v[i]);
#pragma unroll
  for (int o = 32; o; o >>= 1) m = fmaxf(m, __shfl_xor(m, o, 64));
  __shared__ float redm[4];
  if ((t & 63) == 0) redm[t >> 6] = m;
  __syncthreads();
  m = fmaxf(fmaxf(redm[0], redm[1]), fmaxf(redm[2], redm[3]));

  float sum = 0.f;
#pragma unroll
  for (int i = 0; i < 8; i++) { v[i] = __expf(v[i] - m); sum += v[i]; }
#pragma unroll
  for (int o = 32; o; o >>= 1) sum += __shfl_xor(sum, o, 64);
  __shared__ float reds[4];
  if ((t & 63) == 0) reds[t >> 6] = sum;
  __syncthreads();
  sum = reds[0] + reds[1] + reds[2] + reds[3];
  const float r = 1.0f / sum;

  us8 o;
#pragma unroll
  for (int i = 0; i < 8; i++) o[i] = f2bf(v[i] * r);
  p[t] = o;
}

extern "C" void kernel_launch(void* const* d_in, const int* in_sizes, int n_in,
                              void* d_out, int out_size, void* d_ws, size_t ws_size,
                              hipStream_t stream) {
  const float* x   = (const float*)d_in[0];  // [8,2048,1024]
  const float* ctx = (const float*)d_in[1];  // [8,2048,1024]
  const float* Wq  = (const float*)d_in[2];  // [1024,1024]
  const float* Wk  = (const float*)d_in[3];
  const float* Wv  = (const float*)d_in[4];
  float* out = (float*)d_out;                // [8,2048,1024] f32

  const size_t NT = 8ull * 2048 * 1024;      // 16,777,216 elements

  // d_ws layout (u16 elements; total 107 MB):
  //   xbf [0,NT)  cbf [NT,2NT)  -> both dead after projections -> S overlays
  //   Vt  [2NT,3NT)   Wqb/Wkb/Wvb [3NT, 3NT+3M)
  u16* wsu  = (u16*)d_ws;
  u16* xbf  = wsu;
  u16* cbf  = wsu + NT;
  u16* Sbuf = wsu;                 // overlays xbf+cbf (67 MB, 8 batches)
  u16* Vt   = wsu + 2 * NT;
  u16* Wqb  = wsu + 3 * NT;        // Wqb,Wkb,Wvb contiguous (1M elems each)
  // d_out doubles as bf16 Q [0,NT) and K [NT,2NT) until PV overwrites it.
  u16* Qbf = (u16*)d_out;

  dim3 blk(256), gblk(512);

  // 1) converts (2 dispatches)
  cvt_xc<<<dim3(32768), blk, 0, stream>>>((const float4*)x, (const float4*)ctx,
                                          (us4*)xbf, (us4*)cbf);
  cvt_w<<<dim3(3072), blk, 0, stream>>>((const float4*)Wq, (const float4*)Wk,
                                        (const float4*)Wv, (us4*)Wqb);

  // 2) [Q|K] projection: M=16384 N=1024 K=1024, z=0/1. nx*ny*nz=4*64*2=512.
  gemm_nt<true><<<dim3(512), gblk, 0, stream>>>(
      xbf, Wqb, Qbf, 1024, 1024, 1024, 1024,
      (long)NT, 1024L * 1024, (long)NT, 4, 64);
  // Vt[b,e,t] = Wv @ ctx_b^T : M=1024 N=2048 K=1024. nx*ny*nz=8*4*8=256.
  gemm_nt<true><<<dim3(256), gblk, 0, stream>>>(
      Wqb + 2 * 1024 * 1024, cbf, Vt, 1024, 1024, 2048, 1024,
      0L, 2048L * 1024, 1024L * 2048, 8, 4);

  // 3) S = Q@K^T : 8 batches, M=2048 N=2048 K=1024, bf16 out.
  //    nx*ny*nz = 8*8*8 = 512 blocks; slab=64 = one batch per XCD.
  gemm_nt<true><<<dim3(512), gblk, 0, stream>>>(
      Qbf, Qbf + NT, Sbuf, 1024, 1024, 2048, 1024,
      2048L * 1024, 2048L * 1024, 2048L * 2048, 8, 8);

  // 4) softmax in place: 16384 rows of 2048
  softmax_rows_bf16<<<dim3(16384), blk, 0, stream>>>(Sbuf);

  // 5) out = P@Vt^T : M=2048 N=1024 K=2048, f32 out. nx*ny*nz=4*8*8=256 ->
  //    one batch per XCD. Overwrites dead Q/K in d_out (stream-ordered).
  gemm_nt<false><<<dim3(256), gblk, 0, stream>>>(
      Sbuf, Vt, out, 2048, 2048, 1024, 2048,
      2048L * 2048, 1024L * 2048, 2048L * 1024, 4, 8);
}